// Round 19
// baseline (57.704 us; speedup 1.0000x reference)
//
#include <hip/hip_runtime.h>

namespace {

constexpr int BB   = 32;     // batch
constexpr int NBOX = 50;
constexpr int NCLS = 20;
constexpr int NT   = 10647;  // total anchors
constexpr int NNEG = 1000;
constexpr int DEC_BLOCKS = (NT + 63) / 64;          // 167: 64 anchors/block x 4 lanes
constexpr int POS_BLOCKS = (NBOX + 3) / 4;          // 13: 4 boxes/block (1 per wave)
constexpr float EPS = 1e-7f;
constexpr float PI4 = (float)(4.0 / 9.869604401089358);  // 4/pi^2

__device__ __constant__ float c_aw[9] = {10.f/416.f,16.f/416.f,33.f/416.f,30.f/416.f,62.f/416.f,59.f/416.f,116.f/416.f,156.f/416.f,373.f/416.f};
__device__ __constant__ float c_ah[9] = {13.f/416.f,30.f/416.f,23.f/416.f,61.f/416.f,45.f/416.f,119.f/416.f,90.f/416.f,198.f/416.f,326.f/416.f};

// raw v_rcp_f32 (~1 ulp): only feeds discrete decisions (mask + ordering).
__device__ __forceinline__ float fastrcp(float x) {
  return __builtin_amdgcn_rcpf(x);
}

__device__ __forceinline__ float dciou(float al, float at, float ar, float ab,
                                       float bl, float bt, float br, float bb,
                                       float atanA, float atanB) {
  float ltx = fmaxf(al, bl), lty = fmaxf(at, bt);
  float rbx = fminf(ar, br), rby = fminf(ab, bb);
  float wx = fmaxf(rbx - ltx, 0.f), wy = fmaxf(rby - lty, 0.f);
  float inter = wx * wy;
  float wa = ar - al, ha = ab - at;
  float wb = br - bl, hb = bb - bt;
  float uni = wa * ha + wb * hb - inter;
  float iou = inter / (uni + EPS);
  float cw = fmaxf(ar, br) - fminf(al, bl);
  float ch = fmaxf(ab, bb) - fminf(at, bt);
  float c2 = cw * cw + ch * ch + EPS;
  float dx = (al + ar) * 0.5f - (bl + br) * 0.5f;
  float dy = (at + ab) * 0.5f - (bt + bb) * 0.5f;
  float rho2 = dx * dx + dy * dy;
  float dat = atanA - atanB;
  float v = PI4 * (dat * dat);
  float alpha = v / (1.f - iou + v + EPS);
  return iou - rho2 / c2 - alpha * v;
}

// Decode-path CIoU: A={l,t,r,b}, E={cx,cy,atanA,areaA} (register-resident);
// anchor-side values hoisted; divisions via rcp (feeds only discrete decisions).
__device__ __forceinline__ float dciou_h(float4 A, float4 E,
                                         float bl, float bt, float br, float bb,
                                         float areaB,
                                         float cxb, float cyb, float atanB) {
  float ltx = fmaxf(A.x, bl), lty = fmaxf(A.y, bt);
  float rbx = fminf(A.z, br), rby = fminf(A.w, bb);
  float wx = fmaxf(rbx - ltx, 0.f), wy = fmaxf(rby - lty, 0.f);
  float inter = wx * wy;
  float uni = E.w + areaB - inter;
  float iou = inter * fastrcp(uni + EPS);
  float cw = fmaxf(A.z, br) - fminf(A.x, bl);
  float ch = fmaxf(A.w, bb) - fminf(A.y, bt);
  float c2 = cw * cw + ch * ch + EPS;
  float dx = E.x - cxb;
  float dy = E.y - cyb;
  float rho2 = dx * dx + dy * dy;
  float dat = E.z - atanB;
  float v = PI4 * (dat * dat);
  float alpha = v * fastrcp(1.f - iou + v + EPS);
  return iou - rho2 * fastrcp(c2) - alpha * v;
}

__device__ __forceinline__ int wave_incl_scan(int x, int lane) {
  #pragma unroll
  for (int off = 1; off < 64; off <<= 1) {
    int y = __shfl_up(x, off);
    if (lane >= off) x += y;
  }
  return x;
}

// K1 fused: blocks [0,167) = decode+mx — 4 lanes/anchor quad split, box data
// hoisted LDS->registers (13 boxes/lane, padded idempotently with box 49);
// blocks [167,180) = positive losses (1 box per wave).
__global__ __launch_bounds__(256, 3) void k_main(const float* __restrict__ p,
                            const float* __restrict__ boxes,
                            const int* __restrict__ labels,
                            unsigned long long* __restrict__ comp,
                            float* __restrict__ pcls, float* __restrict__ pbox,
                            float* __restrict__ pcp, float* __restrict__ out) {
  const int b = blockIdx.y;
  const int tid = threadIdx.x;
  if (blockIdx.x == 0 && b == 0 && tid == 0) out[0] = 0.f;

  if (blockIdx.x < DEC_BLOCKS) {
    // ---- decode + mx path: 64 anchors/block, 4 lanes per anchor ----
    __shared__ float4 sA[NBOX];   // l,t,r,b
    __shared__ float4 sE[NBOX];   // cx,cy,atanA,areaA
    if (tid < NBOX) {
      const float* bp = boxes + (b * NBOX + tid) * 4;
      float l = bp[0], t = bp[1], r = bp[2], d = bp[3];
      sA[tid] = make_float4(l, t, r, d);
      float wa = r - l, ha = d - t;
      sE[tid] = make_float4((l + r) * 0.5f, (t + d) * 0.5f,
                            atanf(wa / (ha + EPS)), wa * ha);
    }
    __syncthreads();

    const int q = tid & 3;
    const int j = blockIdx.x * 64 + (tid >> 2);
    if (j >= NT) return;

    int lvl = (j < 8112) ? 0 : ((j < 10140) ? 1 : 2);
    int jb0 = (lvl == 0) ? 0 : ((lvl == 1) ? 8112 : 10140);
    int f   = (lvl == 0) ? 52 : ((lvl == 1) ? 26 : 13);
    int jj = j - jb0;
    int cell = jj / 3, a = jj % 3 + lvl * 3;
    int x = cell % f, y = cell / f;
    float ff = (float)f;
    const float* pr = p + ((size_t)b * NT + j) * 25;
    float px = pr[0] / ff + (float)x / ff;
    float py = pr[1] / ff + (float)y / ff;
    float pw = expf(pr[2]) * c_aw[a];
    float ph = expf(pr[3]) * c_ah[a];
    float bl = px - pw * 0.5f, bt = py - ph * 0.5f;
    float br = px + pw * 0.5f, bbv = py + ph * 0.5f;
    float wb = br - bl, hb = bbv - bt;
    float areab = wb * hb;
    float cxb = (bl + br) * 0.5f, cyb = (bt + bbv) * 0.5f;
    float atb = atanf(wb / (hb + EPS));

    // Hoist this lane's 13 boxes {q, q+4, ...} into registers (idx clamped to
    // 49: re-maxing a duplicate box is exactly idempotent for fmax).
    float4 rA[13], rE[13];
    #pragma unroll
    for (int i = 0; i < 13; ++i) {
      int idx = 4 * i + q; idx = (idx < NBOX) ? idx : (NBOX - 1);
      rA[i] = sA[idx];
      rE[i] = sE[idx];
    }
    float mx0 = -INFINITY, mx1 = -INFINITY;
    #pragma unroll
    for (int i = 0; i + 1 < 13; i += 2) {
      float v0 = dciou_h(rA[i],     rE[i],     bl, bt, br, bbv, areab, cxb, cyb, atb);
      float v1 = dciou_h(rA[i + 1], rE[i + 1], bl, bt, br, bbv, areab, cxb, cyb, atb);
      mx0 = fmaxf(mx0, v0);
      mx1 = fmaxf(mx1, v1);
    }
    mx0 = fmaxf(mx0, dciou_h(rA[12], rE[12], bl, bt, br, bbv, areab, cxb, cyb, atb));
    float mx = fmaxf(mx0, mx1);
    // Merge the four quad lanes (exact: max associative/commutative).
    mx = fmaxf(mx, __shfl_xor(mx, 1));
    mx = fmaxf(mx, __shfl_xor(mx, 2));

    if (q == 0) {
      float key = (mx < 0.5f) ? mx : INFINITY;
      unsigned int u = __float_as_uint(key);
      u = (u & 0x80000000u) ? ~u : (u | 0x80000000u);
      comp[(size_t)b * NT + j] = ((unsigned long long)u << 14) | (unsigned long long)j;
    }
  } else {
    // ---- positive-loss path: 4 waves/block, 1 box per wave ----
    const int lane = tid & 63;
    const int wave = tid >> 6;
    const int i = (blockIdx.x - DEC_BLOCKS) * 4 + wave;   // box index

    __shared__ float scx[NBOX], scy[NBOX];
    if (tid < NBOX) {
      const float* bp = boxes + (b * NBOX + tid) * 4;
      float l = bp[0], t = bp[1], r = bp[2], d = bp[3];
      scx[tid] = (l + r) * 0.5f;
      scy[tid] = (t + d) * 0.5f;
    }
    __syncthreads();
    if (i >= NBOX) return;

    const float* bi = boxes + (b * NBOX + i) * 4;
    float bl0 = bi[0], bt0 = bi[1], br0 = bi[2], bd0 = bi[3];
    float fi = (float)i;
    float al = bl0 + fi, at = bt0 + fi, ar = br0 + fi, ad = bd0 + fi;
    float wa = ar - al, ha = ad - at;
    float atanA = atanf(wa / (ha + EPS));

    float bestv = -INFINITY; int bestm = 1 << 30;
    #pragma unroll
    for (int m = lane; m < 9 * NBOX; m += 64) {
      int jb = m / 9, aa = m % 9;
      float fa = (aa < 3) ? 52.f : (aa < 6 ? 26.f : 13.f);
      float col = floorf(scx[jb] * fa);
      float row = floorf(scy[jb] * fa);
      float ax = col / fa, ay = row / fa;
      float aw = c_aw[aa], ah = c_ah[aa];
      float fj = (float)jb;
      float bl = (ax - aw * 0.5f) + fj;
      float bt = (ay - ah * 0.5f) + fj;
      float br = (ax + aw * 0.5f) + fj;
      float bd = (ay + ah * 0.5f) + fj;
      float wb = br - bl, hb = bd - bt;
      float atanB = atanf(wb / (hb + EPS));
      float v = dciou(al, at, ar, ad, bl, bt, br, bd, atanA, atanB);
      if (v > bestv) { bestv = v; bestm = m; }
    }
    #pragma unroll
    for (int off = 32; off > 0; off >>= 1) {
      float ov = __shfl_down(bestv, off);
      int om = __shfl_down(bestm, off);
      if (ov > bestv || (ov == bestv && om < bestm)) { bestv = ov; bestm = om; }
    }
    int bm = __shfl(bestm, 0);

    int k = bm % 9;
    int lvl = k / 3;
    float fk = (k < 3) ? 52.f : (k < 6 ? 26.f : 13.f);
    float col = floorf(scx[i] * fk);
    float row = floorf(scy[i] * fk);
    float offc = (lvl == 0) ? 0.f : (lvl == 1 ? 2704.f : 3380.f);
    int midx = (int)((offc + row * fk + col) * 3.0f + (float)lvl);  // ref: +lvl, not +k%3

    const float* prm = p + ((size_t)b * NT + midx) * 25;
    int lab = labels[b * NBOX + i] - 1;

    float lc = 0.f;
    if (lane < NCLS) {
      float pc = prm[5 + lane];
      pc = fminf(fmaxf(pc, EPS), 1.f - EPS);
      float tt = (lane == lab) ? 1.f : 0.f;
      lc = -(tt * logf(pc) + (1.f - tt) * logf(1.f - pc));
    }
    #pragma unroll
    for (int off = 32; off > 0; off >>= 1) lc += __shfl_down(lc, off);

    if (lane == 0) {
      pcls[b * NBOX + i] = lc;
      float pc4 = prm[4];
      pc4 = fminf(fmaxf(pc4, EPS), 1.f - EPS);
      pcp[b * NBOX + i] = -logf(pc4);

      // Re-derive pred ltrb for row midx (same expressions as reference decode).
      int lvl2 = (midx < 8112) ? 0 : ((midx < 10140) ? 1 : 2);
      int jb0 = (lvl2 == 0) ? 0 : ((lvl2 == 1) ? 8112 : 10140);
      int f2  = (lvl2 == 0) ? 52 : ((lvl2 == 1) ? 26 : 13);
      int jj2 = midx - jb0;
      int cell2 = jj2 / 3, a2 = jj2 % 3 + lvl2 * 3;
      int xx = cell2 % f2, yy = cell2 / f2;
      float ff2 = (float)f2;
      float px = prm[0] / ff2 + (float)xx / ff2;
      float py = prm[1] / ff2 + (float)yy / ff2;
      float pw = expf(prm[2]) * c_aw[a2];
      float ph = expf(prm[3]) * c_ah[a2];
      float pbl = px - pw * 0.5f, pbt = py - ph * 0.5f;
      float pbr = px + pw * 0.5f, pbd = py + ph * 0.5f;

      float wb = pbr - pbl, hb = pbd - pbt;
      float atanB = atanf(wb / (hb + EPS));
      float wa0 = br0 - bl0, ha0 = bd0 - bt0;
      float atanA0 = atanf(wa0 / (ha0 + EPS));
      float cp = dciou(bl0, bt0, br0, bd0, pbl, pbt, pbr, pbd, atanA0, atanB);
      float w = 2.f - wa0 * ha0;
      pbox[b * NBOX + i] = w * (1.f - cp);
    }
  }
}

// K2 (fused select + scan + BCE + final): rank scan, radix select with
// whole-bucket early termination, gather/BCE, fold positive partials,
// atomicAdd the final scalar into out[0].
__global__ __launch_bounds__(1024) void k_neg2(const unsigned long long* __restrict__ comp,
                                               const float* __restrict__ p,
                                               const float* __restrict__ pcls,
                                               const float* __restrict__ pbox,
                                               const float* __restrict__ pcp,
                                               float* __restrict__ out) {
  int b = blockIdx.x;
  const unsigned long long* c = comp + (size_t)b * NT;
  const int tid = threadIdx.x, lane = tid & 63, wave = tid >> 6;

  __shared__ int hist[4096];
  __shared__ int s_w[16];
  __shared__ unsigned long long s_pref;
  __shared__ int s_rem;
  __shared__ int s_digit;
  __shared__ int s_rem_next;
  __shared__ int s_csel;
  __shared__ int s_done;
  __shared__ int s_cnt;
  __shared__ float s_facc[16];
  __shared__ float s_lcn;
  __shared__ int s_tot[11][16];
  __shared__ int s_off[11][16];

  // Hoist the image's composites into registers: 11 per thread (chunk-major).
  unsigned long long v[11];
  #pragma unroll
  for (int k = 0; k < 11; ++k) {
    int j = k * 1024 + tid;
    v[k] = (j < NT) ? c[j] : ~0ull;   // pad > any 46-bit composite
  }

  // Rank scan: per-chunk wave scans (no barriers), one wave scans the 176
  // (chunk,wave) totals. Also yields the total mask count.
  int wincl[11];
  #pragma unroll
  for (int k = 0; k < 11; ++k) {
    unsigned long long x = v[k];
    int flag = ((x >> 14) < 0xFF800000ull) ? 1 : 0;  // finite ordkey => masked
    int incl = wave_incl_scan(flag, lane);
    wincl[k] = incl;
    if (lane == 63) s_tot[k][wave] = incl;
  }
  __syncthreads();
  if (wave == 0) {
    int i0 = lane * 3;
    int a0 = (i0     < 176) ? s_tot[i0 / 16][i0 % 16] : 0;
    int a1 = (i0 + 1 < 176) ? s_tot[(i0 + 1) / 16][(i0 + 1) % 16] : 0;
    int a2 = (i0 + 2 < 176) ? s_tot[(i0 + 2) / 16][(i0 + 2) % 16] : 0;
    int lsum = a0 + a1 + a2;
    int linc = wave_incl_scan(lsum, lane);
    int lexc = linc - lsum;
    if (i0     < 176) s_off[i0 / 16][i0 % 16] = lexc;
    if (i0 + 1 < 176) s_off[(i0 + 1) / 16][(i0 + 1) % 16] = lexc + a0;
    if (i0 + 2 < 176) s_off[(i0 + 2) / 16][(i0 + 2) % 16] = lexc + a0 + a1;
    if (lane == 63) s_cnt = linc;   // total masked count
  }
  if (tid == 0) { s_pref = 0ull; s_rem = NNEG - 1; s_done = 0; }
  __syncthreads();
  const bool spec = (s_cnt >= NNEG);  // target guaranteed among finite keys

  // Radix passes over windows [47:36],[35:24],[23:12],[11:0], with
  // whole-bucket early termination.
  for (int pass = 0; pass < 4; ++pass) {
    if (s_done) break;   // uniform (set before prior barrier)
    int lo = 36 - pass * 12;
    for (int h = tid; h < 4096; h += 1024) hist[h] = 0;
    __syncthreads();
    unsigned long long pref = s_pref;
    #pragma unroll
    for (int k = 0; k < 11; ++k) {
      unsigned long long x = v[k];
      bool fin = ((x >> 14) < 0xFF800000ull);
      if ((!spec || fin) && (x >> (lo + 12)) == (pref >> (lo + 12)))
        atomicAdd(&hist[(int)((x >> lo) & 4095ull)], 1);
    }
    __syncthreads();
    // Block-wide exclusive scan over 4096 buckets (4 per thread), locate target.
    int base = tid * 4;
    int c0 = hist[base], c1 = hist[base + 1], c2 = hist[base + 2], c3 = hist[base + 3];
    int tsum = c0 + c1 + c2 + c3;
    int incl = wave_incl_scan(tsum, lane);
    if (lane == 63) s_w[wave] = incl;
    __syncthreads();
    if (wave == 0) {
      int wv = (lane < 16) ? s_w[lane] : 0;
      int wincl2 = wave_incl_scan(wv, lane);
      if (lane < 16) s_w[lane] = wincl2 - wv;  // exclusive wave offsets
    }
    __syncthreads();
    int excl = incl - tsum + s_w[wave];
    int rem = s_rem;
    int p0 = excl, p1 = p0 + c0, p2 = p1 + c1, p3 = p2 + c2;
    if (rem >= p0 && rem < p0 + c0) { s_digit = base + 0; s_rem_next = rem - p0; s_csel = c0; }
    if (rem >= p1 && rem < p1 + c1) { s_digit = base + 1; s_rem_next = rem - p1; s_csel = c1; }
    if (rem >= p2 && rem < p2 + c2) { s_digit = base + 2; s_rem_next = rem - p2; s_csel = c2; }
    if (rem >= p3 && rem < p3 + c3) { s_digit = base + 3; s_rem_next = rem - p3; s_csel = c3; }
    __syncthreads();
    if (tid == 0) {
      s_pref |= ((unsigned long long)s_digit) << lo;
      s_rem = s_rem_next;
      if (s_rem_next == s_csel - 1) {       // need the ENTIRE bucket
        s_pref |= (lo > 0) ? ((1ull << lo) - 1ull) : 0ull;
        s_done = 1;
      }
    }
    __syncthreads();
  }
  const unsigned long long T = s_pref;  // covers exactly the 1000 smallest

  // Barrier-free gather + BCE using precomputed rank offsets.
  float acc = 0.f;
  const float* pb = p + (size_t)b * NT * 25;
  #pragma unroll
  for (int k = 0; k < 11; ++k) {
    unsigned long long x = v[k];
    if (x <= T) {
      int idx = s_off[k][wave] + wincl[k] - 1;
      if (idx < 0) idx += NT;  // JAX negative-index wrap (rank can be -1)
      float q = 1.f - pb[(size_t)idx * 25 + 4];
      q = fminf(fmaxf(q, EPS), 1.f - EPS);
      acc += -logf(q);
    }
  }

  // Reduce acc across the block -> s_lcn.
  #pragma unroll
  for (int off = 32; off > 0; off >>= 1) acc += __shfl_down(acc, off);
  if (lane == 0) s_facc[wave] = acc;
  __syncthreads();
  if (tid == 0) {
    float s = 0.f;
    #pragma unroll
    for (int w = 0; w < 16; ++w) s += s_facc[w];
    s_lcn = s;
  }
  __syncthreads();

  // Fold in this image's positive partials and accumulate the final scalar.
  if (wave == 0) {
    float s3 = 0.f;
    if (lane < NBOX)
      s3 = pcls[b * NBOX + lane] + pbox[b * NBOX + lane] + pcp[b * NBOX + lane];
    #pragma unroll
    for (int off = 32; off > 0; off >>= 1) s3 += __shfl_down(s3, off);
    if (lane == 0)
      atomicAdd(out, (s3 / (float)NBOX + s_lcn) / (float)BB);
  }
}

}  // namespace

extern "C" void kernel_launch(void* const* d_in, const int* in_sizes, int n_in,
                              void* d_out, int out_size, void* d_ws, size_t ws_size,
                              hipStream_t stream) {
  const float* p      = (const float*)d_in[0];
  const float* boxes  = (const float*)d_in[1];
  const int*   labels = (const int*)d_in[2];
  float* out = (float*)d_out;

  char* ws = (char*)d_ws;
  size_t off = 0;
  unsigned long long* comp = (unsigned long long*)(ws + off); off += (size_t)BB * NT * sizeof(unsigned long long);
  float* pcls = (float*)(ws + off);                off += BB * NBOX * sizeof(float);
  float* pbox = (float*)(ws + off);                off += BB * NBOX * sizeof(float);
  float* pcp  = (float*)(ws + off);                off += BB * NBOX * sizeof(float);

  dim3 g1(DEC_BLOCKS + POS_BLOCKS, BB);
  k_main<<<g1, 256, 0, stream>>>(p, boxes, labels, comp, pcls, pbox, pcp, out);
  k_neg2<<<BB, 1024, 0, stream>>>(comp, p, pcls, pbox, pcp, out);
}

// Round 20
// 51.888 us; speedup vs baseline: 1.1121x; 1.1121x over previous
//
#include <hip/hip_runtime.h>

namespace {

constexpr int BB   = 32;     // batch
constexpr int NBOX = 50;
constexpr int NCLS = 20;
constexpr int NT   = 10647;  // total anchors
constexpr int NNEG = 1000;
constexpr int DEC_BLOCKS = (NT + 127) / 128;        // 84: 128 anchors/block x 2 lanes
constexpr int POS_BLOCKS = (NBOX + 3) / 4;          // 13: 4 boxes/block (1 per wave)
constexpr float EPS = 1e-7f;
constexpr float PI4 = (float)(4.0 / 9.869604401089358);  // 4/pi^2

__device__ __constant__ float c_aw[9] = {10.f/416.f,16.f/416.f,33.f/416.f,30.f/416.f,62.f/416.f,59.f/416.f,116.f/416.f,156.f/416.f,373.f/416.f};
__device__ __constant__ float c_ah[9] = {13.f/416.f,30.f/416.f,23.f/416.f,61.f/416.f,45.f/416.f,119.f/416.f,90.f/416.f,198.f/416.f,326.f/416.f};

// raw v_rcp_f32 (~1 ulp): only feeds discrete decisions (mask + ordering).
__device__ __forceinline__ float fastrcp(float x) {
  return __builtin_amdgcn_rcpf(x);
}

__device__ __forceinline__ float dciou(float al, float at, float ar, float ab,
                                       float bl, float bt, float br, float bb,
                                       float atanA, float atanB) {
  float ltx = fmaxf(al, bl), lty = fmaxf(at, bt);
  float rbx = fminf(ar, br), rby = fminf(ab, bb);
  float wx = fmaxf(rbx - ltx, 0.f), wy = fmaxf(rby - lty, 0.f);
  float inter = wx * wy;
  float wa = ar - al, ha = ab - at;
  float wb = br - bl, hb = bb - bt;
  float uni = wa * ha + wb * hb - inter;
  float iou = inter / (uni + EPS);
  float cw = fmaxf(ar, br) - fminf(al, bl);
  float ch = fmaxf(ab, bb) - fminf(at, bt);
  float c2 = cw * cw + ch * ch + EPS;
  float dx = (al + ar) * 0.5f - (bl + br) * 0.5f;
  float dy = (at + ab) * 0.5f - (bt + bb) * 0.5f;
  float rho2 = dx * dx + dy * dy;
  float dat = atanA - atanB;
  float v = PI4 * (dat * dat);
  float alpha = v / (1.f - iou + v + EPS);
  return iou - rho2 / c2 - alpha * v;
}

// Decode-path CIoU: A={l,t,r,b}, E={cx,cy,atanA,areaA} (register-resident);
// anchor-side values hoisted; divisions via rcp (feeds only discrete decisions).
__device__ __forceinline__ float dciou_h(float4 A, float4 E,
                                         float bl, float bt, float br, float bb,
                                         float areaB,
                                         float cxb, float cyb, float atanB) {
  float ltx = fmaxf(A.x, bl), lty = fmaxf(A.y, bt);
  float rbx = fminf(A.z, br), rby = fminf(A.w, bb);
  float wx = fmaxf(rbx - ltx, 0.f), wy = fmaxf(rby - lty, 0.f);
  float inter = wx * wy;
  float uni = E.w + areaB - inter;
  float iou = inter * fastrcp(uni + EPS);
  float cw = fmaxf(A.z, br) - fminf(A.x, bl);
  float ch = fmaxf(A.w, bb) - fminf(A.y, bt);
  float c2 = cw * cw + ch * ch + EPS;
  float dx = E.x - cxb;
  float dy = E.y - cyb;
  float rho2 = dx * dx + dy * dy;
  float dat = E.z - atanB;
  float v = PI4 * (dat * dat);
  float alpha = v * fastrcp(1.f - iou + v + EPS);
  return iou - rho2 * fastrcp(c2) - alpha * v;
}

__device__ __forceinline__ int wave_incl_scan(int x, int lane) {
  #pragma unroll
  for (int off = 1; off < 64; off <<= 1) {
    int y = __shfl_up(x, off);
    if (lane >= off) x += y;
  }
  return x;
}

// K1 fused: blocks [0,84) = decode+mx (2 lanes/anchor parity split; box data
// hoisted LDS->registers once, box loop fully unrolled pure-VALU; bounds
// (256,2) gives a 256-VGPR budget); blocks [84,97) = positive losses.
__global__ __launch_bounds__(256, 2) void k_main(const float* __restrict__ p,
                            const float* __restrict__ boxes,
                            const int* __restrict__ labels,
                            unsigned long long* __restrict__ comp,
                            float* __restrict__ pcls, float* __restrict__ pbox,
                            float* __restrict__ pcp, float* __restrict__ out) {
  const int b = blockIdx.y;
  const int tid = threadIdx.x;
  if (blockIdx.x == 0 && b == 0 && tid == 0) out[0] = 0.f;

  if (blockIdx.x < DEC_BLOCKS) {
    // ---- decode + mx path: 128 anchors/block, 2 lanes per anchor ----
    __shared__ float4 sA[NBOX];   // l,t,r,b
    __shared__ float4 sE[NBOX];   // cx,cy,atanA,areaA
    if (tid < NBOX) {
      const float* bp = boxes + (b * NBOX + tid) * 4;
      float l = bp[0], t = bp[1], r = bp[2], d = bp[3];
      sA[tid] = make_float4(l, t, r, d);
      float wa = r - l, ha = d - t;
      sE[tid] = make_float4((l + r) * 0.5f, (t + d) * 0.5f,
                            atanf(wa / (ha + EPS)), wa * ha);
    }
    __syncthreads();

    const int par = tid & 1;
    const int j = blockIdx.x * 128 + (tid >> 1);
    if (j >= NT) return;

    int lvl = (j < 8112) ? 0 : ((j < 10140) ? 1 : 2);
    int jb0 = (lvl == 0) ? 0 : ((lvl == 1) ? 8112 : 10140);
    int f   = (lvl == 0) ? 52 : ((lvl == 1) ? 26 : 13);
    int jj = j - jb0;
    int cell = jj / 3, a = jj % 3 + lvl * 3;
    int x = cell % f, y = cell / f;
    float ff = (float)f;
    const float* pr = p + ((size_t)b * NT + j) * 25;
    float px = pr[0] / ff + (float)x / ff;
    float py = pr[1] / ff + (float)y / ff;
    float pw = expf(pr[2]) * c_aw[a];
    float ph = expf(pr[3]) * c_ah[a];
    float bl = px - pw * 0.5f, bt = py - ph * 0.5f;
    float br = px + pw * 0.5f, bbv = py + ph * 0.5f;
    float wb = br - bl, hb = bbv - bt;
    float areab = wb * hb;
    float cxb = (bl + br) * 0.5f, cyb = (bt + bbv) * 0.5f;
    float atb = atanf(wb / (hb + EPS));

    // Hoist this lane's 25 boxes from LDS into registers (50 back-to-back
    // broadcast ds_reads, fully pipelined), then a fully-unrolled pure-VALU
    // dual-chain loop. Exact: fmax regrouping is associative/commutative.
    float4 rA[25], rE[25];
    #pragma unroll
    for (int i = 0; i < 25; ++i) {
      rA[i] = sA[2 * i + par];
      rE[i] = sE[2 * i + par];
    }
    float mx0 = -INFINITY, mx1 = -INFINITY;
    #pragma unroll
    for (int i = 0; i + 1 < 25; i += 2) {
      float v0 = dciou_h(rA[i],     rE[i],     bl, bt, br, bbv, areab, cxb, cyb, atb);
      float v1 = dciou_h(rA[i + 1], rE[i + 1], bl, bt, br, bbv, areab, cxb, cyb, atb);
      mx0 = fmaxf(mx0, v0);
      mx1 = fmaxf(mx1, v1);
    }
    mx0 = fmaxf(mx0, dciou_h(rA[24], rE[24], bl, bt, br, bbv, areab, cxb, cyb, atb));
    float mx = fmaxf(mx0, mx1);
    // Merge the two parity halves.
    mx = fmaxf(mx, __shfl_xor(mx, 1));

    if (par == 0) {
      float key = (mx < 0.5f) ? mx : INFINITY;
      unsigned int u = __float_as_uint(key);
      u = (u & 0x80000000u) ? ~u : (u | 0x80000000u);
      comp[(size_t)b * NT + j] = ((unsigned long long)u << 14) | (unsigned long long)j;
    }
  } else {
    // ---- positive-loss path: 4 waves/block, 1 box per wave ----
    const int lane = tid & 63;
    const int wave = tid >> 6;
    const int i = (blockIdx.x - DEC_BLOCKS) * 4 + wave;   // box index

    __shared__ float scx[NBOX], scy[NBOX];
    if (tid < NBOX) {
      const float* bp = boxes + (b * NBOX + tid) * 4;
      float l = bp[0], t = bp[1], r = bp[2], d = bp[3];
      scx[tid] = (l + r) * 0.5f;
      scy[tid] = (t + d) * 0.5f;
    }
    __syncthreads();
    if (i >= NBOX) return;

    const float* bi = boxes + (b * NBOX + i) * 4;
    float bl0 = bi[0], bt0 = bi[1], br0 = bi[2], bd0 = bi[3];
    float fi = (float)i;
    float al = bl0 + fi, at = bt0 + fi, ar = br0 + fi, ad = bd0 + fi;
    float wa = ar - al, ha = ad - at;
    float atanA = atanf(wa / (ha + EPS));

    float bestv = -INFINITY; int bestm = 1 << 30;
    #pragma unroll
    for (int m = lane; m < 9 * NBOX; m += 64) {
      int jb = m / 9, aa = m % 9;
      float fa = (aa < 3) ? 52.f : (aa < 6 ? 26.f : 13.f);
      float col = floorf(scx[jb] * fa);
      float row = floorf(scy[jb] * fa);
      float ax = col / fa, ay = row / fa;
      float aw = c_aw[aa], ah = c_ah[aa];
      float fj = (float)jb;
      float bl = (ax - aw * 0.5f) + fj;
      float bt = (ay - ah * 0.5f) + fj;
      float br = (ax + aw * 0.5f) + fj;
      float bd = (ay + ah * 0.5f) + fj;
      float wb = br - bl, hb = bd - bt;
      float atanB = atanf(wb / (hb + EPS));
      float v = dciou(al, at, ar, ad, bl, bt, br, bd, atanA, atanB);
      if (v > bestv) { bestv = v; bestm = m; }
    }
    #pragma unroll
    for (int off = 32; off > 0; off >>= 1) {
      float ov = __shfl_down(bestv, off);
      int om = __shfl_down(bestm, off);
      if (ov > bestv || (ov == bestv && om < bestm)) { bestv = ov; bestm = om; }
    }
    int bm = __shfl(bestm, 0);

    int k = bm % 9;
    int lvl = k / 3;
    float fk = (k < 3) ? 52.f : (k < 6 ? 26.f : 13.f);
    float col = floorf(scx[i] * fk);
    float row = floorf(scy[i] * fk);
    float offc = (lvl == 0) ? 0.f : (lvl == 1 ? 2704.f : 3380.f);
    int midx = (int)((offc + row * fk + col) * 3.0f + (float)lvl);  // ref: +lvl, not +k%3

    const float* prm = p + ((size_t)b * NT + midx) * 25;
    int lab = labels[b * NBOX + i] - 1;

    float lc = 0.f;
    if (lane < NCLS) {
      float pc = prm[5 + lane];
      pc = fminf(fmaxf(pc, EPS), 1.f - EPS);
      float tt = (lane == lab) ? 1.f : 0.f;
      lc = -(tt * logf(pc) + (1.f - tt) * logf(1.f - pc));
    }
    #pragma unroll
    for (int off = 32; off > 0; off >>= 1) lc += __shfl_down(lc, off);

    if (lane == 0) {
      pcls[b * NBOX + i] = lc;
      float pc4 = prm[4];
      pc4 = fminf(fmaxf(pc4, EPS), 1.f - EPS);
      pcp[b * NBOX + i] = -logf(pc4);

      // Re-derive pred ltrb for row midx (same expressions as reference decode).
      int lvl2 = (midx < 8112) ? 0 : ((midx < 10140) ? 1 : 2);
      int jb0 = (lvl2 == 0) ? 0 : ((lvl2 == 1) ? 8112 : 10140);
      int f2  = (lvl2 == 0) ? 52 : ((lvl2 == 1) ? 26 : 13);
      int jj2 = midx - jb0;
      int cell2 = jj2 / 3, a2 = jj2 % 3 + lvl2 * 3;
      int xx = cell2 % f2, yy = cell2 / f2;
      float ff2 = (float)f2;
      float px = prm[0] / ff2 + (float)xx / ff2;
      float py = prm[1] / ff2 + (float)yy / ff2;
      float pw = expf(prm[2]) * c_aw[a2];
      float ph = expf(prm[3]) * c_ah[a2];
      float pbl = px - pw * 0.5f, pbt = py - ph * 0.5f;
      float pbr = px + pw * 0.5f, pbd = py + ph * 0.5f;

      float wb = pbr - pbl, hb = pbd - pbt;
      float atanB = atanf(wb / (hb + EPS));
      float wa0 = br0 - bl0, ha0 = bd0 - bt0;
      float atanA0 = atanf(wa0 / (ha0 + EPS));
      float cp = dciou(bl0, bt0, br0, bd0, pbl, pbt, pbr, pbd, atanA0, atanB);
      float w = 2.f - wa0 * ha0;
      pbox[b * NBOX + i] = w * (1.f - cp);
    }
  }
}

// K2 (fused select + scan + BCE + final): rank scan, radix select with
// whole-bucket early termination, gather/BCE, fold positive partials,
// atomicAdd the final scalar into out[0].
__global__ __launch_bounds__(1024) void k_neg2(const unsigned long long* __restrict__ comp,
                                               const float* __restrict__ p,
                                               const float* __restrict__ pcls,
                                               const float* __restrict__ pbox,
                                               const float* __restrict__ pcp,
                                               float* __restrict__ out) {
  int b = blockIdx.x;
  const unsigned long long* c = comp + (size_t)b * NT;
  const int tid = threadIdx.x, lane = tid & 63, wave = tid >> 6;

  __shared__ int hist[4096];
  __shared__ int s_w[16];
  __shared__ unsigned long long s_pref;
  __shared__ int s_rem;
  __shared__ int s_digit;
  __shared__ int s_rem_next;
  __shared__ int s_csel;
  __shared__ int s_done;
  __shared__ int s_cnt;
  __shared__ float s_facc[16];
  __shared__ float s_lcn;
  __shared__ int s_tot[11][16];
  __shared__ int s_off[11][16];

  // Hoist the image's composites into registers: 11 per thread (chunk-major).
  unsigned long long v[11];
  #pragma unroll
  for (int k = 0; k < 11; ++k) {
    int j = k * 1024 + tid;
    v[k] = (j < NT) ? c[j] : ~0ull;   // pad > any 46-bit composite
  }

  // Rank scan: per-chunk wave scans (no barriers), one wave scans the 176
  // (chunk,wave) totals. Also yields the total mask count.
  int wincl[11];
  #pragma unroll
  for (int k = 0; k < 11; ++k) {
    unsigned long long x = v[k];
    int flag = ((x >> 14) < 0xFF800000ull) ? 1 : 0;  // finite ordkey => masked
    int incl = wave_incl_scan(flag, lane);
    wincl[k] = incl;
    if (lane == 63) s_tot[k][wave] = incl;
  }
  __syncthreads();
  if (wave == 0) {
    int i0 = lane * 3;
    int a0 = (i0     < 176) ? s_tot[i0 / 16][i0 % 16] : 0;
    int a1 = (i0 + 1 < 176) ? s_tot[(i0 + 1) / 16][(i0 + 1) % 16] : 0;
    int a2 = (i0 + 2 < 176) ? s_tot[(i0 + 2) / 16][(i0 + 2) % 16] : 0;
    int lsum = a0 + a1 + a2;
    int linc = wave_incl_scan(lsum, lane);
    int lexc = linc - lsum;
    if (i0     < 176) s_off[i0 / 16][i0 % 16] = lexc;
    if (i0 + 1 < 176) s_off[(i0 + 1) / 16][(i0 + 1) % 16] = lexc + a0;
    if (i0 + 2 < 176) s_off[(i0 + 2) / 16][(i0 + 2) % 16] = lexc + a0 + a1;
    if (lane == 63) s_cnt = linc;   // total masked count
  }
  if (tid == 0) { s_pref = 0ull; s_rem = NNEG - 1; s_done = 0; }
  __syncthreads();
  const bool spec = (s_cnt >= NNEG);  // target guaranteed among finite keys

  // Radix passes over windows [47:36],[35:24],[23:12],[11:0], with
  // whole-bucket early termination.
  for (int pass = 0; pass < 4; ++pass) {
    if (s_done) break;   // uniform (set before prior barrier)
    int lo = 36 - pass * 12;
    for (int h = tid; h < 4096; h += 1024) hist[h] = 0;
    __syncthreads();
    unsigned long long pref = s_pref;
    #pragma unroll
    for (int k = 0; k < 11; ++k) {
      unsigned long long x = v[k];
      bool fin = ((x >> 14) < 0xFF800000ull);
      if ((!spec || fin) && (x >> (lo + 12)) == (pref >> (lo + 12)))
        atomicAdd(&hist[(int)((x >> lo) & 4095ull)], 1);
    }
    __syncthreads();
    // Block-wide exclusive scan over 4096 buckets (4 per thread), locate target.
    int base = tid * 4;
    int c0 = hist[base], c1 = hist[base + 1], c2 = hist[base + 2], c3 = hist[base + 3];
    int tsum = c0 + c1 + c2 + c3;
    int incl = wave_incl_scan(tsum, lane);
    if (lane == 63) s_w[wave] = incl;
    __syncthreads();
    if (wave == 0) {
      int wv = (lane < 16) ? s_w[lane] : 0;
      int wincl2 = wave_incl_scan(wv, lane);
      if (lane < 16) s_w[lane] = wincl2 - wv;  // exclusive wave offsets
    }
    __syncthreads();
    int excl = incl - tsum + s_w[wave];
    int rem = s_rem;
    int p0 = excl, p1 = p0 + c0, p2 = p1 + c1, p3 = p2 + c2;
    if (rem >= p0 && rem < p0 + c0) { s_digit = base + 0; s_rem_next = rem - p0; s_csel = c0; }
    if (rem >= p1 && rem < p1 + c1) { s_digit = base + 1; s_rem_next = rem - p1; s_csel = c1; }
    if (rem >= p2 && rem < p2 + c2) { s_digit = base + 2; s_rem_next = rem - p2; s_csel = c2; }
    if (rem >= p3 && rem < p3 + c3) { s_digit = base + 3; s_rem_next = rem - p3; s_csel = c3; }
    __syncthreads();
    if (tid == 0) {
      s_pref |= ((unsigned long long)s_digit) << lo;
      s_rem = s_rem_next;
      if (s_rem_next == s_csel - 1) {       // need the ENTIRE bucket
        s_pref |= (lo > 0) ? ((1ull << lo) - 1ull) : 0ull;
        s_done = 1;
      }
    }
    __syncthreads();
  }
  const unsigned long long T = s_pref;  // covers exactly the 1000 smallest

  // Barrier-free gather + BCE using precomputed rank offsets.
  float acc = 0.f;
  const float* pb = p + (size_t)b * NT * 25;
  #pragma unroll
  for (int k = 0; k < 11; ++k) {
    unsigned long long x = v[k];
    if (x <= T) {
      int idx = s_off[k][wave] + wincl[k] - 1;
      if (idx < 0) idx += NT;  // JAX negative-index wrap (rank can be -1)
      float q = 1.f - pb[(size_t)idx * 25 + 4];
      q = fminf(fmaxf(q, EPS), 1.f - EPS);
      acc += -logf(q);
    }
  }

  // Reduce acc across the block -> s_lcn.
  #pragma unroll
  for (int off = 32; off > 0; off >>= 1) acc += __shfl_down(acc, off);
  if (lane == 0) s_facc[wave] = acc;
  __syncthreads();
  if (tid == 0) {
    float s = 0.f;
    #pragma unroll
    for (int w = 0; w < 16; ++w) s += s_facc[w];
    s_lcn = s;
  }
  __syncthreads();

  // Fold in this image's positive partials and accumulate the final scalar.
  if (wave == 0) {
    float s3 = 0.f;
    if (lane < NBOX)
      s3 = pcls[b * NBOX + lane] + pbox[b * NBOX + lane] + pcp[b * NBOX + lane];
    #pragma unroll
    for (int off = 32; off > 0; off >>= 1) s3 += __shfl_down(s3, off);
    if (lane == 0)
      atomicAdd(out, (s3 / (float)NBOX + s_lcn) / (float)BB);
  }
}

}  // namespace

extern "C" void kernel_launch(void* const* d_in, const int* in_sizes, int n_in,
                              void* d_out, int out_size, void* d_ws, size_t ws_size,
                              hipStream_t stream) {
  const float* p      = (const float*)d_in[0];
  const float* boxes  = (const float*)d_in[1];
  const int*   labels = (const int*)d_in[2];
  float* out = (float*)d_out;

  char* ws = (char*)d_ws;
  size_t off = 0;
  unsigned long long* comp = (unsigned long long*)(ws + off); off += (size_t)BB * NT * sizeof(unsigned long long);
  float* pcls = (float*)(ws + off);                off += BB * NBOX * sizeof(float);
  float* pbox = (float*)(ws + off);                off += BB * NBOX * sizeof(float);
  float* pcp  = (float*)(ws + off);                off += BB * NBOX * sizeof(float);

  dim3 g1(DEC_BLOCKS + POS_BLOCKS, BB);
  k_main<<<g1, 256, 0, stream>>>(p, boxes, labels, comp, pcls, pbox, pcp, out);
  k_neg2<<<BB, 1024, 0, stream>>>(comp, p, pcls, pbox, pcp, out);
}